// Round 2
// baseline (398.222 us; speedup 1.0000x reference)
//
#include <hip/hip_runtime.h>

// ---------------------------------------------------------------------------
// Fused MHA (T5-style rel-bias, mask, softmax) + attn tensor materialization.
// B=4 H=8 S=2048 D=512 Dk=Dv=64.  All matmuls in bf16 MFMA 16x16x32.
// Pipeline: conv_w -> conv_x -> gemm_proj(qh,kh,vt) -> attn_k -> gemm_final.
// vt is stored transposed [b][h][d][s] so PV B-frags are contiguous reads.
// ---------------------------------------------------------------------------

typedef __attribute__((ext_vector_type(8))) short bfrag;   // 8 x bf16 (4 VGPR)
typedef __attribute__((ext_vector_type(4))) float f32x4;
typedef unsigned int u32;

#define MFMA16(a,b,c) __builtin_amdgcn_mfma_f32_16x16x32_bf16(a,b,c,0,0,0)

__device__ __forceinline__ void gl_lds16(const void* g, void* l){
  __builtin_amdgcn_global_load_lds((const __attribute__((address_space(1))) u32*)g,
                                   (__attribute__((address_space(3))) u32*)l, 16, 0, 0);
}
__device__ __forceinline__ short f2bs(float f){   // f32 -> bf16 bits, RNE
  u32 u = __float_as_uint(f);
  u = (u + 0x7fffu + ((u>>16)&1u)) >> 16;
  return (short)u;
}
__device__ __forceinline__ float b2f(short s){
  return __uint_as_float(((u32)(unsigned short)s) << 16);
}

#define BB 4
#define HH 8
#define SS 2048
#define DD 512

// workspace byte offsets (total ~58 MB)
#define WQT_OFF  0u
#define WKT_OFF  524288u
#define WVT_OFF  1048576u
#define WFCT_OFF 1572864u
#define QB_OFF   2097152u
#define KB_OFF   10485760u
#define VB_OFF   18874368u
#define QH_OFF   27262976u
#define KH_OFF   35651584u
#define VT_OFF   44040192u
#define OH_OFF   52428800u

// ------------------------- converts --------------------------------------
__global__ __launch_bounds__(256) void conv_w_k(const float* w0,const float* w1,
                                                const float* w2,const float* w3, char* ws){
  const float* w; short* o;
  switch(blockIdx.z){
    case 0:  w=w0; o=(short*)(ws+WQT_OFF); break;
    case 1:  w=w1; o=(short*)(ws+WKT_OFF); break;
    case 2:  w=w2; o=(short*)(ws+WVT_OFF); break;
    default: w=w3; o=(short*)(ws+WFCT_OFF); break;
  }
  int t  = blockIdx.x*256 + threadIdx.x;   // 32768 threads: 512 rows x 64
  int n  = t >> 6;
  int k0 = (t & 63) << 3;
  bfrag v;
  #pragma unroll
  for (int j=0;j<8;++j) v[j] = f2bs(w[(k0+j)*512 + n]);   // Wt[n][k] = W[k][n]
  *(bfrag*)(o + n*512 + k0) = v;
}

__global__ __launch_bounds__(256) void conv_x_k(const float* x0,const float* x1,
                                                const float* x2, char* ws){
  const float* x; short* o;
  switch(blockIdx.z){
    case 0:  x=x0; o=(short*)(ws+QB_OFF); break;
    case 1:  x=x1; o=(short*)(ws+KB_OFF); break;
    default: x=x2; o=(short*)(ws+VB_OFF); break;
  }
  int i = (blockIdx.x*256 + threadIdx.x) << 3;
  float4 a = *(const float4*)(x+i);
  float4 b = *(const float4*)(x+i+4);
  bfrag v;
  v[0]=f2bs(a.x); v[1]=f2bs(a.y); v[2]=f2bs(a.z); v[3]=f2bs(a.w);
  v[4]=f2bs(b.x); v[5]=f2bs(b.y); v[6]=f2bs(b.z); v[7]=f2bs(b.w);
  *(bfrag*)(o+i) = v;
}

// ------------------------- generic bt-GEMM core ---------------------------
// C[i][j] = sum_k A[i][k]*Bt[j][k], K=512, tile 128x128, BK=64, 4 waves 2x2.
// mode 0: C bf16 -> qh/kh [b][h][s][64]   (i=s_g, j=h*64+d)
// mode 1: C bf16 -> vt [b][h][d][s]       (i=h*64+d, j=s_g)
// mode 2: C fp32 -> out                   (i*512+j)
__device__ void gemm_core(const short* A, const short* Bt, char* Cout, int mode, int bid){
  __shared__ __align__(16) char lds[32768];
  int i0, j0;
  if (mode==1){ i0 = (bid&3)<<7; j0 = (bid>>2)<<7; }
  else        { i0 = (bid>>2)<<7; j0 = (bid&3)<<7; }
  int tid = threadIdx.x;
  int l = tid & 63, w = tid >> 6;
  int wr = (w>>1)<<6, wc = (w&1)<<6;
  int l15 = l & 15, l4 = l >> 4;
  f32x4 acc[4][4];
  #pragma unroll
  for(int a=0;a<4;++a)
    #pragma unroll
    for(int b=0;b<4;++b) acc[a][b] = (f32x4){0.f,0.f,0.f,0.f};
  const char* Ab = (const char*)A;
  const char* Bb = (const char*)Bt;
  for (int kk=0; kk<8; ++kk){
    #pragma unroll
    for (int it=0; it<4; ++it){
      int ci = it*256 + tid;
      int row = ci>>3, cc = ci&7;
      gl_lds16(Ab + (size_t)(i0+row)*1024 + kk*128 + ((cc^(row&7))<<4),
               lds + ((it*256 + w*64)<<4));
      gl_lds16(Bb + (size_t)(j0+row)*1024 + kk*128 + ((cc^(row&7))<<4),
               lds + 16384 + ((it*256 + w*64)<<4));
    }
    asm volatile("s_waitcnt vmcnt(0)" ::: "memory");
    __syncthreads();
    #pragma unroll
    for (int kb=0; kb<2; ++kb){
      bfrag af[4], bf[4];
      #pragma unroll
      for (int mi=0;mi<4;++mi){
        int row = wr + mi*16 + l15;
        af[mi] = *(const bfrag*)(lds + row*128 + (((kb*4 + l4) ^ (row&7))<<4));
      }
      #pragma unroll
      for (int ni=0;ni<4;++ni){
        int row = wc + ni*16 + l15;
        bf[ni] = *(const bfrag*)(lds + 16384 + row*128 + (((kb*4 + l4) ^ (row&7))<<4));
      }
      #pragma unroll
      for (int mi=0;mi<4;++mi)
        #pragma unroll
        for (int ni=0;ni<4;++ni)
          acc[mi][ni] = MFMA16(af[mi], bf[ni], acc[mi][ni]);
    }
    __syncthreads();
  }
  #pragma unroll
  for (int mi=0;mi<4;++mi){
    #pragma unroll
    for (int ni=0;ni<4;++ni){
      #pragma unroll
      for (int r=0;r<4;++r){
        int i = i0 + wr + mi*16 + (l4<<2) + r;
        int j = j0 + wc + ni*16 + l15;
        float v = acc[mi][ni][r];
        if (mode==2){
          ((float*)Cout)[(size_t)i*512 + j] = v;
        } else if (mode==0){
          size_t o = ((size_t)(((i>>11)<<3) + (j>>6))*2048 + (size_t)(i&2047))*64 + (j&63);
          ((short*)Cout)[o] = f2bs(v);
        } else {
          size_t o = ((size_t)(((j>>11)<<3) + (i>>6))*64 + (size_t)(i&63))*2048 + (j&2047);
          ((short*)Cout)[o] = f2bs(v);
        }
      }
    }
  }
}

__global__ __launch_bounds__(256,2) void gemm_proj_k(char* ws){
  switch(blockIdx.z){
    case 0:  gemm_core((const short*)(ws+QB_OFF),  (const short*)(ws+WQT_OFF), ws+QH_OFF, 0, blockIdx.x); break;
    case 1:  gemm_core((const short*)(ws+KB_OFF),  (const short*)(ws+WKT_OFF), ws+KH_OFF, 0, blockIdx.x); break;
    default: gemm_core((const short*)(ws+WVT_OFF), (const short*)(ws+VB_OFF),  ws+VT_OFF, 1, blockIdx.x); break;
  }
}
__global__ __launch_bounds__(256,2) void gemm_final_k(char* ws, float* out){
  gemm_core((const short*)(ws+OH_OFF), (const short*)(ws+WFCT_OFF), (char*)out, 2, blockIdx.x);
}

// ------------------------- fused attention --------------------------------
// block = 32 q-rows x full S. 4 waves. LDS: p[32][2048] bf16 (swizzled) +
// K/V double-buffer 2x8KB + mask(f32) + bias + sums.
#define P_SZ      131072
#define KV_OFF_L  131072
#define MSK_OFF_L 147456
#define BIAS_OFF_L 155648
#define WSUM_OFF_L 155808
#define RECIP_OFF_L 156064
#define LDS_TOTAL  156192

__global__ __launch_bounds__(256,1) void attn_k(char* ws, const int* mask,
                                                const float* rel_bias, float* attn_out){
  extern __shared__ __align__(16) char sm[];
  int tid = threadIdx.x;
  int l = tid & 63, w = tid >> 6;
  int l15 = l & 15, l4 = l >> 4;
  int qblk = blockIdx.x, bh = blockIdx.y;
  int b = bh >> 3, h = bh & 7;
  const short* qhb = (const short*)(ws+QH_OFF) + (size_t)bh*SS*64;
  const char*  khb = ws + KH_OFF + (size_t)bh*SS*128;    // 128 B per k-row
  const char*  vtb = ws + VT_OFF + (size_t)bh*64*SS*2;   // 4096 B per d-row

  // mask -> LDS f32 (0/1), bias row for this head -> LDS
  {
    const int4* m4 = (const int4*)(mask + b*SS);
    int4 ma = m4[tid*2], mb = m4[tid*2+1];
    float4* mf = (float4*)(sm + MSK_OFF_L);
    mf[tid*2]   = make_float4(ma.x?1.f:0.f, ma.y?1.f:0.f, ma.z?1.f:0.f, ma.w?1.f:0.f);
    mf[tid*2+1] = make_float4(mb.x?1.f:0.f, mb.y?1.f:0.f, mb.z?1.f:0.f, mb.w?1.f:0.f);
  }
  if (tid < 33) ((float*)(sm+BIAS_OFF_L))[tid] = rel_bias[tid*HH + h];

  int wrow  = (w>>1)<<4;             // 0 or 16 (q-rows of this wave pair)
  int qrow0 = (qblk<<5) + wrow;
  bfrag qf0 = *(const bfrag*)(qhb + (size_t)(qrow0 + l15)*64 + l4*8);
  bfrag qf1 = *(const bfrag*)(qhb + (size_t)(qrow0 + l15)*64 + 32 + l4*8);
  float rsum[4] = {0.f,0.f,0.f,0.f};
  char* kv0 = sm + KV_OFF_L;
  char* kv1 = sm + KV_OFF_L + 8192;
  const float* biasl = (const float*)(sm+BIAS_OFF_L);
  const float* maskl = (const float*)(sm+MSK_OFF_L);

  auto stageK = [&](int kc){
    const char* kt = khb + (size_t)kc*8192;           // 64 kpos * 128 B
    char* dst = (kc&1)?kv1:kv0;
    #pragma unroll
    for (int it=0; it<2; ++it){
      int ci = it*256 + tid;
      int row = ci>>3, cc = ci&7;
      gl_lds16(kt + row*128 + ((cc^(row&7))<<4), dst + ((it*256 + w*64)<<4));
    }
  };
  auto stageV = [&](int vc){
    char* dst = (vc&1)?kv1:kv0;
    #pragma unroll
    for (int it=0; it<2; ++it){
      int ci = it*256 + tid;
      int row = ci>>3, cc = ci&7;                     // row = d (0..63)
      gl_lds16(vtb + (size_t)row*4096 + (vc<<7) + ((cc^(row&7))<<4),
               dst + ((it*256 + w*64)<<4));
    }
  };

  stageK(0); stageK(1);
  __syncthreads();                                    // mask/bias visible

  // ---- QK^T + exp phase: 32 iters of 64 kpos ----
  for (int kc=0; kc<32; ++kc){
    if (kc<31) { asm volatile("s_waitcnt vmcnt(2)" ::: "memory"); }
    else       { asm volatile("s_waitcnt vmcnt(0)" ::: "memory"); }
    __builtin_amdgcn_s_barrier();
    const char* kb = (kc&1)?kv1:kv0;
    int colb = (w&1)<<5;
    #pragma unroll
    for (int ct=0; ct<2; ++ct){
      int rowk = colb + (ct<<4) + l15;
      bfrag b0 = *(const bfrag*)(kb + rowk*128 + (((l4  )^(rowk&7))<<4));
      bfrag b1 = *(const bfrag*)(kb + rowk*128 + (((4+l4)^(rowk&7))<<4));
      f32x4 acc = (f32x4){0.f,0.f,0.f,0.f};
      acc = MFMA16(qf0, b0, acc);
      acc = MFMA16(qf1, b1, acc);
      int kpos = (kc<<6) + rowk;
      float mval = maskl[kpos];
      int rl0 = wrow + (l4<<2);
      int qg0 = (qblk<<5) + rl0;
      #pragma unroll
      for (int r=0;r<4;++r){
        int n = qg0 + r - kpos;
        n = n<0 ? 0 : (n>32 ? 32 : n);
        float s = acc[r]*0.125f + biasl[n];
        float p = mval * __expf(s);                   // no max-sub: |s|<~10
        rsum[r] += p;
        int rowl = rl0 + r;
        int byte = kpos<<1;
        int ch = (byte>>4) ^ (rowl&15);               // XOR-swizzle chunks
        *(short*)(sm + rowl*4096 + (ch<<4) + (byte&15)) = f2bs(p);
      }
    }
    __builtin_amdgcn_s_barrier();
    if (kc+2<32) stageK(kc+2);
  }

  // prefetch V tiles 0,1 (kv bufs free)
  stageV(0); stageV(1);

  // ---- row-sum reduction ----
  {
    float* wsum = (float*)(sm+WSUM_OFF_L);
    #pragma unroll
    for (int r=0;r<4;++r){
      float s = rsum[r];
      s += __shfl_xor(s,1); s += __shfl_xor(s,2);
      s += __shfl_xor(s,4); s += __shfl_xor(s,8);
      if (l15==0) wsum[w*16 + (l4<<2) + r] = s;
    }
  }
  __syncthreads();
  if (tid < 32){
    float* wsum = (float*)(sm+WSUM_OFF_L);
    float t = (tid<16) ? (wsum[tid] + wsum[16+tid])
                       : (wsum[32+(tid&15)] + wsum[48+(tid&15)]);
    ((float*)(sm+RECIP_OFF_L))[tid] = 1.f/t;
  }
  __syncthreads();
  const float* recip = (const float*)(sm+RECIP_OFF_L);

  // ---- PV phase: 32 iters of 64 kpos ----
  f32x4 acco0 = (f32x4){0.f,0.f,0.f,0.f}, acco1 = (f32x4){0.f,0.f,0.f,0.f};
  int dbase = (w&1)<<5;
  int prow = wrow + l15;
  for (int vc=0; vc<32; ++vc){
    if (vc<31) { asm volatile("s_waitcnt vmcnt(2)" ::: "memory"); }
    else       { asm volatile("s_waitcnt vmcnt(0)" ::: "memory"); }
    __builtin_amdgcn_s_barrier();
    const char* vb = (vc&1)?kv1:kv0;
    #pragma unroll
    for (int m=0;m<2;++m){
      int pcol = (vc<<6) + (m<<5) + (l4<<3);
      int pch = (pcol>>3) ^ (prow&15);
      bfrag af = *(const bfrag*)(sm + prow*4096 + (pch<<4));
      {
        int drow = dbase + l15;
        bfrag bv = *(const bfrag*)(vb + drow*128 + ((((m<<2)+l4)^(drow&7))<<4));
        acco0 = MFMA16(af, bv, acco0);
      }
      {
        int drow = dbase + 16 + l15;
        bfrag bv = *(const bfrag*)(vb + drow*128 + ((((m<<2)+l4)^(drow&7))<<4));
        acco1 = MFMA16(af, bv, acco1);
      }
    }
    __builtin_amdgcn_s_barrier();
    if (vc+2<32) stageV(vc+2);
  }

  // ---- oh epilogue (bf16 head-concat output) ----
  {
    short* oh = (short*)(ws + OH_OFF);
    #pragma unroll
    for (int r=0;r<4;++r){
      int rowl = wrow + (l4<<2) + r;
      float rc = recip[rowl];
      size_t sg = (size_t)b*SS + (qblk<<5) + rowl;
      oh[sg*512 + h*64 + dbase + l15]      = f2bs(acco0[r]*rc);
      oh[sg*512 + h*64 + dbase + 16 + l15] = f2bs(acco1[r]*rc);
    }
  }

  // ---- stream normalized attn to global (nontemporal, coalesced) ----
  {
    float* dst0 = attn_out + (size_t)bh*SS*SS + (size_t)(qblk<<5)*SS;
    #pragma unroll
    for (int rr=0; rr<8; ++rr){
      int rowl = (w<<3) + rr;
      float rc = recip[rowl];
      float* dst = dst0 + (size_t)rowl*SS;
      #pragma unroll
      for (int it=0; it<4; ++it){
        int col = it*512 + (l<<3);
        int ch = (col>>3) ^ (rowl&15);
        bfrag pv = *(const bfrag*)(sm + rowl*4096 + (ch<<4));
        f32x4 o0 = (f32x4){b2f(pv[0])*rc, b2f(pv[1])*rc, b2f(pv[2])*rc, b2f(pv[3])*rc};
        f32x4 o1 = (f32x4){b2f(pv[4])*rc, b2f(pv[5])*rc, b2f(pv[6])*rc, b2f(pv[7])*rc};
        __builtin_nontemporal_store(o0, (f32x4*)(dst+col));
        __builtin_nontemporal_store(o1, (f32x4*)(dst+col+4));
      }
    }
  }
}

// ------------------------- launch -----------------------------------------
extern "C" void kernel_launch(void* const* d_in, const int* in_sizes, int n_in,
                              void* d_out, int out_size, void* d_ws, size_t ws_size,
                              hipStream_t stream){
  const float* q   = (const float*)d_in[0];
  const float* k   = (const float*)d_in[1];
  const float* v   = (const float*)d_in[2];
  const int*  mask = (const int*)  d_in[3];
  const float* Wq  = (const float*)d_in[4];
  const float* Wk  = (const float*)d_in[5];
  const float* Wv  = (const float*)d_in[6];
  const float* Wfc = (const float*)d_in[7];
  const float* rb  = (const float*)d_in[8];
  char* ws = (char*)d_ws;
  float* out  = (float*)d_out;
  float* attn = out + (size_t)BB*SS*512;

  (void)hipFuncSetAttribute((const void*)attn_k,
        hipFuncAttributeMaxDynamicSharedMemorySize, LDS_TOTAL);

  conv_w_k<<<dim3(128,1,4), 256, 0, stream>>>(Wq, Wk, Wv, Wfc, ws);
  conv_x_k<<<dim3(2048,1,3), 256, 0, stream>>>(q, k, v, ws);
  gemm_proj_k<<<dim3(256,1,3), 256, 0, stream>>>(ws);
  attn_k<<<dim3(64,32), 256, LDS_TOTAL, stream>>>(ws, mask, rb, attn);
  gemm_final_k<<<dim3(256,1,1), 256, 0, stream>>>(ws, out);
}

// Round 3
// 366.300 us; speedup vs baseline: 1.0871x; 1.0871x over previous
//
#include <hip/hip_runtime.h>

// ---------------------------------------------------------------------------
// Fused MHA (T5-style rel-bias, mask, softmax) + attn tensor materialization.
// B=4 H=8 S=2048 D=512 Dk=Dv=64.  All matmuls in bf16 MFMA 16x16x32.
// Pipeline: conv_w -> conv_x -> gemm_proj(qh,kh,vt) -> attn_k -> gemm_final.
// attn_k: 512 thr / 8 waves per block (R2: was 4 waves; occupancy was 11%).
// ---------------------------------------------------------------------------

typedef __attribute__((ext_vector_type(8))) short bfrag;   // 8 x bf16 (4 VGPR)
typedef __attribute__((ext_vector_type(4))) float f32x4;
typedef unsigned int u32;

#define MFMA16(a,b,c) __builtin_amdgcn_mfma_f32_16x16x32_bf16(a,b,c,0,0,0)

__device__ __forceinline__ void gl_lds16(const void* g, void* l){
  __builtin_amdgcn_global_load_lds((const __attribute__((address_space(1))) u32*)g,
                                   (__attribute__((address_space(3))) u32*)l, 16, 0, 0);
}
__device__ __forceinline__ short f2bs(float f){   // f32 -> bf16 bits, RNE
  u32 u = __float_as_uint(f);
  u = (u + 0x7fffu + ((u>>16)&1u)) >> 16;
  return (short)u;
}
__device__ __forceinline__ float b2f(short s){
  return __uint_as_float(((u32)(unsigned short)s) << 16);
}

#define BB 4
#define HH 8
#define SS 2048
#define DD 512

// workspace byte offsets (total ~58 MB)
#define WQT_OFF  0u
#define WKT_OFF  524288u
#define WVT_OFF  1048576u
#define WFCT_OFF 1572864u
#define QB_OFF   2097152u
#define KB_OFF   10485760u
#define VB_OFF   18874368u
#define QH_OFF   27262976u
#define KH_OFF   35651584u
#define VT_OFF   44040192u
#define OH_OFF   52428800u

// ------------------------- converts --------------------------------------
__global__ __launch_bounds__(256) void conv_w_k(const float* w0,const float* w1,
                                                const float* w2,const float* w3, char* ws){
  const float* w; short* o;
  switch(blockIdx.z){
    case 0:  w=w0; o=(short*)(ws+WQT_OFF); break;
    case 1:  w=w1; o=(short*)(ws+WKT_OFF); break;
    case 2:  w=w2; o=(short*)(ws+WVT_OFF); break;
    default: w=w3; o=(short*)(ws+WFCT_OFF); break;
  }
  int t  = blockIdx.x*256 + threadIdx.x;   // 32768 threads: 512 rows x 64
  int n  = t >> 6;
  int k0 = (t & 63) << 3;
  bfrag v;
  #pragma unroll
  for (int j=0;j<8;++j) v[j] = f2bs(w[(k0+j)*512 + n]);   // Wt[n][k] = W[k][n]
  *(bfrag*)(o + n*512 + k0) = v;
}

__global__ __launch_bounds__(256) void conv_x_k(const float* x0,const float* x1,
                                                const float* x2, char* ws){
  const float* x; short* o;
  switch(blockIdx.z){
    case 0:  x=x0; o=(short*)(ws+QB_OFF); break;
    case 1:  x=x1; o=(short*)(ws+KB_OFF); break;
    default: x=x2; o=(short*)(ws+VB_OFF); break;
  }
  int i = (blockIdx.x*256 + threadIdx.x) << 3;
  float4 a = *(const float4*)(x+i);
  float4 b = *(const float4*)(x+i+4);
  bfrag v;
  v[0]=f2bs(a.x); v[1]=f2bs(a.y); v[2]=f2bs(a.z); v[3]=f2bs(a.w);
  v[4]=f2bs(b.x); v[5]=f2bs(b.y); v[6]=f2bs(b.z); v[7]=f2bs(b.w);
  *(bfrag*)(o+i) = v;
}

// ------------------------- generic bt-GEMM core ---------------------------
// C[i][j] = sum_k A[i][k]*Bt[j][k], K=512, tile 128x128, BK=64, 4 waves 2x2.
// mode 0: C bf16 -> qh/kh [b][h][s][64]   (i=s_g, j=h*64+d)
// mode 1: C bf16 -> vt [b][h][d][s]       (i=h*64+d, j=s_g)
// mode 2: C fp32 -> out                   (i*512+j)
__device__ void gemm_core(const short* A, const short* Bt, char* Cout, int mode, int bid){
  __shared__ __align__(16) char lds[32768];
  int i0, j0;
  if (mode==1){ i0 = (bid&3)<<7; j0 = (bid>>2)<<7; }
  else        { i0 = (bid>>2)<<7; j0 = (bid&3)<<7; }
  int tid = threadIdx.x;
  int l = tid & 63, w = tid >> 6;
  int wr = (w>>1)<<6, wc = (w&1)<<6;
  int l15 = l & 15, l4 = l >> 4;
  f32x4 acc[4][4];
  #pragma unroll
  for(int a=0;a<4;++a)
    #pragma unroll
    for(int b=0;b<4;++b) acc[a][b] = (f32x4){0.f,0.f,0.f,0.f};
  const char* Ab = (const char*)A;
  const char* Bb = (const char*)Bt;
  for (int kk=0; kk<8; ++kk){
    #pragma unroll
    for (int it=0; it<4; ++it){
      int ci = it*256 + tid;
      int row = ci>>3, cc = ci&7;
      gl_lds16(Ab + (size_t)(i0+row)*1024 + kk*128 + ((cc^(row&7))<<4),
               lds + ((it*256 + w*64)<<4));
      gl_lds16(Bb + (size_t)(j0+row)*1024 + kk*128 + ((cc^(row&7))<<4),
               lds + 16384 + ((it*256 + w*64)<<4));
    }
    asm volatile("s_waitcnt vmcnt(0)" ::: "memory");
    __syncthreads();
    #pragma unroll
    for (int kb=0; kb<2; ++kb){
      bfrag af[4], bf[4];
      #pragma unroll
      for (int mi=0;mi<4;++mi){
        int row = wr + mi*16 + l15;
        af[mi] = *(const bfrag*)(lds + row*128 + (((kb*4 + l4) ^ (row&7))<<4));
      }
      #pragma unroll
      for (int ni=0;ni<4;++ni){
        int row = wc + ni*16 + l15;
        bf[ni] = *(const bfrag*)(lds + 16384 + row*128 + (((kb*4 + l4) ^ (row&7))<<4));
      }
      #pragma unroll
      for (int mi=0;mi<4;++mi)
        #pragma unroll
        for (int ni=0;ni<4;++ni)
          acc[mi][ni] = MFMA16(af[mi], bf[ni], acc[mi][ni]);
    }
    __syncthreads();
  }
  #pragma unroll
  for (int mi=0;mi<4;++mi){
    #pragma unroll
    for (int ni=0;ni<4;++ni){
      #pragma unroll
      for (int r=0;r<4;++r){
        int i = i0 + wr + mi*16 + (l4<<2) + r;
        int j = j0 + wc + ni*16 + l15;
        float v = acc[mi][ni][r];
        if (mode==2){
          ((float*)Cout)[(size_t)i*512 + j] = v;
        } else if (mode==0){
          size_t o = ((size_t)(((i>>11)<<3) + (j>>6))*2048 + (size_t)(i&2047))*64 + (j&63);
          ((short*)Cout)[o] = f2bs(v);
        } else {
          size_t o = ((size_t)(((j>>11)<<3) + (i>>6))*64 + (size_t)(i&63))*2048 + (j&2047);
          ((short*)Cout)[o] = f2bs(v);
        }
      }
    }
  }
}

__global__ __launch_bounds__(256,2) void gemm_proj_k(char* ws){
  switch(blockIdx.z){
    case 0:  gemm_core((const short*)(ws+QB_OFF),  (const short*)(ws+WQT_OFF), ws+QH_OFF, 0, blockIdx.x); break;
    case 1:  gemm_core((const short*)(ws+KB_OFF),  (const short*)(ws+WKT_OFF), ws+KH_OFF, 0, blockIdx.x); break;
    default: gemm_core((const short*)(ws+WVT_OFF), (const short*)(ws+VB_OFF),  ws+VT_OFF, 1, blockIdx.x); break;
  }
}
__global__ __launch_bounds__(256,2) void gemm_final_k(char* ws, float* out){
  gemm_core((const short*)(ws+OH_OFF), (const short*)(ws+WFCT_OFF), (char*)out, 2, blockIdx.x);
}

// ------------------------- fused attention --------------------------------
// block = 32 q-rows x full S. 8 waves (512 thr). LDS: p[32][2048] bf16
// (chunk-XOR swizzled) + K/V double-buffer 2x8KB + mask(f32) + bias + sums.
// wave w: wq=w>>2 selects q-row half (16 rows), wk=w&3 selects kpos/d tile.
#define KV_OFF_L    131072
#define MSK_OFF_L   147456
#define BIAS_OFF_L  155648
#define WSUM_OFF_L  155808
#define RECIP_OFF_L 156320
#define LDS_TOTAL   156448

__global__ __launch_bounds__(512,1) void attn_k(char* ws, const int* mask,
                                                const float* rel_bias, float* attn_out){
  extern __shared__ __align__(16) char sm[];
  int tid = threadIdx.x;
  int l = tid & 63, w = tid >> 6;
  int l15 = l & 15, l4 = l >> 4;
  int wq = w >> 2, wk = w & 3;
  int qblk = blockIdx.x, bh = blockIdx.y;
  int b = bh >> 3, h = bh & 7;
  const short* qhb = (const short*)(ws+QH_OFF) + (size_t)bh*SS*64;
  const char*  khb = ws + KH_OFF + (size_t)bh*SS*128;    // 128 B per k-row
  const char*  vtb = ws + VT_OFF + (size_t)bh*64*SS*2;   // 4096 B per d-row

  // mask -> LDS f32 (0/1), bias row for this head -> LDS
  {
    const int4* m4 = (const int4*)(mask + b*SS);
    int4 ma = m4[tid];
    float4* mf = (float4*)(sm + MSK_OFF_L);
    mf[tid] = make_float4(ma.x?1.f:0.f, ma.y?1.f:0.f, ma.z?1.f:0.f, ma.w?1.f:0.f);
  }
  if (tid < 33) ((float*)(sm+BIAS_OFF_L))[tid] = rel_bias[tid*HH + h];

  int wrow  = wq << 4;               // 0 or 16 (q-rows of this wave)
  int qrow0 = (qblk<<5) + wrow;
  bfrag qf0 = *(const bfrag*)(qhb + (size_t)(qrow0 + l15)*64 + l4*8);
  bfrag qf1 = *(const bfrag*)(qhb + (size_t)(qrow0 + l15)*64 + 32 + l4*8);
  float rsum[4] = {0.f,0.f,0.f,0.f};
  char* kv0 = sm + KV_OFF_L;
  char* kv1 = sm + KV_OFF_L + 8192;
  const float* biasl = (const float*)(sm+BIAS_OFF_L);
  const float* maskl = (const float*)(sm+MSK_OFF_L);

  // one global_load_lds per wave per tile (512 thr x 16 B = 8 KB tile)
  auto stageK = [&](int kc){
    const char* kt = khb + (size_t)kc*8192;           // 64 kpos * 128 B
    char* dst = (kc&1)?kv1:kv0;
    int row = tid>>3, cc = tid&7;
    gl_lds16(kt + row*128 + ((cc^(row&7))<<4), dst + (tid<<4));
  };
  auto stageV = [&](int vc){
    char* dst = (vc&1)?kv1:kv0;
    int row = tid>>3, cc = tid&7;                     // row = d (0..63)
    gl_lds16(vtb + (size_t)row*4096 + (vc<<7) + ((cc^(row&7))<<4),
             dst + (tid<<4));
  };

  stageK(0); stageK(1);
  __syncthreads();                                    // mask/bias visible

  // ---- QK^T + exp phase: 32 iters of 64 kpos, 1 tile (16 kpos) per wave ----
  for (int kc=0; kc<32; ++kc){
    if (kc<31) { asm volatile("s_waitcnt vmcnt(1)" ::: "memory"); }
    else       { asm volatile("s_waitcnt vmcnt(0)" ::: "memory"); }
    __builtin_amdgcn_s_barrier();
    const char* kb = (kc&1)?kv1:kv0;
    int rowk = (wk<<4) + l15;
    bfrag b0 = *(const bfrag*)(kb + rowk*128 + (((l4  )^(rowk&7))<<4));
    bfrag b1 = *(const bfrag*)(kb + rowk*128 + (((4+l4)^(rowk&7))<<4));
    f32x4 acc = (f32x4){0.f,0.f,0.f,0.f};
    acc = MFMA16(qf0, b0, acc);
    acc = MFMA16(qf1, b1, acc);
    int kpos = (kc<<6) + rowk;
    float mval = maskl[kpos];
    int rl0 = wrow + (l4<<2);
    int qg0 = (qblk<<5) + rl0;
    #pragma unroll
    for (int r=0;r<4;++r){
      int n = qg0 + r - kpos;
      n = n<0 ? 0 : (n>32 ? 32 : n);
      float s = acc[r]*0.125f + biasl[n];
      float p = mval * __expf(s);                     // no max-sub: |s|<~10
      rsum[r] += p;
      int rowl = rl0 + r;
      int byte = kpos<<1;
      int ch = (byte>>4) ^ (rowl&15);                 // XOR-swizzle chunks
      *(short*)(sm + rowl*4096 + (ch<<4) + (byte&15)) = f2bs(p);
    }
    __builtin_amdgcn_s_barrier();
    if (kc+2<32) stageK(kc+2);
  }

  // prefetch V tiles 0,1 (kv bufs free)
  stageV(0); stageV(1);

  // ---- row-sum reduction (4 waves per q-half) ----
  {
    float* wsum = (float*)(sm+WSUM_OFF_L);
    #pragma unroll
    for (int r=0;r<4;++r){
      float s = rsum[r];
      s += __shfl_xor(s,1); s += __shfl_xor(s,2);
      s += __shfl_xor(s,4); s += __shfl_xor(s,8);
      if (l15==0) wsum[w*16 + (l4<<2) + r] = s;
    }
  }
  __syncthreads();
  if (tid < 32){
    float* wsum = (float*)(sm+WSUM_OFF_L);
    int iq = tid >> 4, i = tid & 15;
    float t = wsum[(iq*4+0)*16 + i] + wsum[(iq*4+1)*16 + i]
            + wsum[(iq*4+2)*16 + i] + wsum[(iq*4+3)*16 + i];
    ((float*)(sm+RECIP_OFF_L))[tid] = 1.f/t;
  }
  __syncthreads();
  const float* recip = (const float*)(sm+RECIP_OFF_L);

  // ---- PV phase: 32 iters of 64 kpos, 1 output tile (16 rows x 16 d) / wave ----
  f32x4 acco = (f32x4){0.f,0.f,0.f,0.f};
  int dbase = wk << 4;
  int prow = wrow + l15;
  for (int vc=0; vc<32; ++vc){
    if (vc<31) { asm volatile("s_waitcnt vmcnt(1)" ::: "memory"); }
    else       { asm volatile("s_waitcnt vmcnt(0)" ::: "memory"); }
    __builtin_amdgcn_s_barrier();
    const char* vb = (vc&1)?kv1:kv0;
    #pragma unroll
    for (int m=0;m<2;++m){
      int pcol = (vc<<6) + (m<<5) + (l4<<3);
      int pch = (pcol>>3) ^ (prow&15);
      bfrag af = *(const bfrag*)(sm + prow*4096 + (pch<<4));
      int drow = dbase + l15;
      bfrag bv = *(const bfrag*)(vb + drow*128 + ((((m<<2)+l4)^(drow&7))<<4));
      acco = MFMA16(af, bv, acco);
    }
    __builtin_amdgcn_s_barrier();
    if (vc+2<32) stageV(vc+2);
  }

  // ---- oh epilogue (bf16 head-concat output) ----
  {
    short* oh = (short*)(ws + OH_OFF);
    #pragma unroll
    for (int r=0;r<4;++r){
      int rowl = wrow + (l4<<2) + r;
      float rc = recip[rowl];
      size_t sg = (size_t)b*SS + (qblk<<5) + rowl;
      oh[sg*512 + h*64 + dbase + l15] = f2bs(acco[r]*rc);
    }
  }

  // ---- stream normalized attn to global (nontemporal, coalesced) ----
  {
    float* dst0 = attn_out + (size_t)bh*SS*SS + (size_t)(qblk<<5)*SS;
    #pragma unroll
    for (int rr=0; rr<4; ++rr){
      int rowl = (w<<2) + rr;
      float rc = recip[rowl];
      float* dst = dst0 + (size_t)rowl*SS;
      #pragma unroll
      for (int it=0; it<4; ++it){
        int col = it*512 + (l<<3);
        int ch = (col>>3) ^ (rowl&15);
        bfrag pv = *(const bfrag*)(sm + rowl*4096 + (ch<<4));
        f32x4 o0 = (f32x4){b2f(pv[0])*rc, b2f(pv[1])*rc, b2f(pv[2])*rc, b2f(pv[3])*rc};
        f32x4 o1 = (f32x4){b2f(pv[4])*rc, b2f(pv[5])*rc, b2f(pv[6])*rc, b2f(pv[7])*rc};
        __builtin_nontemporal_store(o0, (f32x4*)(dst+col));
        __builtin_nontemporal_store(o1, (f32x4*)(dst+col+4));
      }
    }
  }
}

// ------------------------- launch -----------------------------------------
extern "C" void kernel_launch(void* const* d_in, const int* in_sizes, int n_in,
                              void* d_out, int out_size, void* d_ws, size_t ws_size,
                              hipStream_t stream){
  const float* q   = (const float*)d_in[0];
  const float* k   = (const float*)d_in[1];
  const float* v   = (const float*)d_in[2];
  const int*  mask = (const int*)  d_in[3];
  const float* Wq  = (const float*)d_in[4];
  const float* Wk  = (const float*)d_in[5];
  const float* Wv  = (const float*)d_in[6];
  const float* Wfc = (const float*)d_in[7];
  const float* rb  = (const float*)d_in[8];
  char* ws = (char*)d_ws;
  float* out  = (float*)d_out;
  float* attn = out + (size_t)BB*SS*512;

  (void)hipFuncSetAttribute((const void*)attn_k,
        hipFuncAttributeMaxDynamicSharedMemorySize, LDS_TOTAL);

  conv_w_k<<<dim3(128,1,4), 256, 0, stream>>>(Wq, Wk, Wv, Wfc, ws);
  conv_x_k<<<dim3(2048,1,3), 256, 0, stream>>>(q, k, v, ws);
  gemm_proj_k<<<dim3(256,1,3), 256, 0, stream>>>(ws);
  attn_k<<<dim3(64,32), 512, LDS_TOTAL, stream>>>(ws, mask, rb, attn);
  gemm_final_k<<<dim3(256,1,1), 256, 0, stream>>>(ws, out);
}